// Round 19
// baseline (25.363 us; speedup 1.0000x reference)
//
#include <hip/hip_runtime.h>
#include <stdint.h>

// Deformable 3x3 local correlation. f16 channel-major SPLIT-CELL LDS (r18,
// 21.1us) + T14 half-split staging: lo half (ch0-7) staged straight, then hi
// half's global loads ISSUE-EARLY / WRITE-LATE interleaved with lo-half
// compute (8-reg flight, store-before-next-load). Per-s setup recomputed per
// half (no state arrays -> stays under the hard 64-VGPR cap).
// r16 lesson: cells must stay 16B-aligned for b128.
// r6-r13 lesson: VGPR cap not overridable; WRITE_SIZE >> 9.2MB = spill.
// left/right (2,128,64,256) f32, extra_offset (2,18,64,256) f32,
// out (2,72,64,256) f32. GROUPS=8, cg=16, S=9.

#define NB 2
#define CC 128
#define HH 64
#define WW 256
#define GG 8
#define CG 16
#define SS 9
#define HW (HH * WW)
#define TY 4                      // output rows per block
#define RW 5                      // staged rows h0-RW .. h0+TY+RW-1 (14 interior)
#define NSLOT 16                  // 1 top guard + 14 data + 1 bottom guard
#define HALFDW 1056               // dwords per half-row (258 cells x 4dw, padded)
#define SLOTQ (2 * HALFDW)        // 2112 dwords per row slot
#define SMEMDW (NSLOT * SLOTQ)    // 33792 dw = 135.2 KB -> 1 block/CU

typedef __fp16 h2v __attribute__((ext_vector_type(2)));

static __device__ __forceinline__ uint32_t pkrtz(float a, float b) {
    h2v v = __builtin_amdgcn_cvt_pkrtz(a, b);
    return __builtin_bit_cast(uint32_t, v);
}
static __device__ __forceinline__ h2v u2h(uint32_t u) {
    return __builtin_bit_cast(h2v, u);
}

#if __has_builtin(__builtin_amdgcn_fdot2)
#define FDOT2(A, B, C) __builtin_amdgcn_fdot2((A), (B), (C), false)
#else
#define FDOT2(A, B, C) fmaf((float)(A).x, (float)(B).x, \
                            fmaf((float)(A).y, (float)(B).y, (C)))
#endif

// 8-channel dot at one (row,col) cell: one aligned b128, 4 fdot2
#define DOT8(P, L0, L1, L2, L3, RES)                                           \
  {                                                                            \
    const uint4 u_ = *(const uint4*)(P);                                       \
    RES = FDOT2(u2h(u_.x), u2h(L0),                                            \
          FDOT2(u2h(u_.y), u2h(L1),                                            \
          FDOT2(u2h(u_.z), u2h(L2),                                            \
          FDOT2(u2h(u_.w), u2h(L3), 0.0f))));                                  \
  }

// one s, one half (PHALF = 0 or HALFDW; CHB = 0 or 8; L* = packed left pairs)
#define SHALF(S, PHALF, CHB, L0, L1, L2, L3)                                   \
  {                                                                            \
    const float x = (float)((S) / 3 - 1) + eob[(2 * (S)) * HW] + (float)wcol;  \
    const float y = (float)((S) % 3 - 1) + eob[(2 * (S) + 1) * HW] + (float)h; \
    const float x0f = floorf(x), y0f = floorf(y);                              \
    const float fx0 = x - x0f, fx1 = 1.0f - fx0;                               \
    const float fy0 = y - y0f, fy1 = 1.0f - fy0;                               \
    const int x0 = (int)x0f, y0 = (int)y0f;                                    \
    const int x1 = x0 + 1, y1 = y0 + 1;                                        \
    const bool vx0 = (unsigned)x0 < (unsigned)WW;                              \
    const bool vx1 = (unsigned)x1 < (unsigned)WW;                              \
    const bool vy0 = (unsigned)y0 < (unsigned)HH;                              \
    const bool vy1 = (unsigned)y1 < (unsigned)HH;                              \
    const float wA = (vx0 && vy0) ? fx1 * fy1 : 0.0f;                          \
    const float wB = (vx1 && vy0) ? fx0 * fy1 : 0.0f;                          \
    const float wC = (vx0 && vy1) ? fx1 * fy0 : 0.0f;                          \
    const float wD = (vx1 && vy1) ? fx0 * fy0 : 0.0f;                          \
    const bool bad = (vy0 && (y0 < row0 || y0 > row_last)) ||                  \
                     (vy1 && (y1 < row0 || y1 > row_last));                    \
    if (__builtin_expect(!bad, 1)) {                                           \
      const int xc = min(max(x0, -1), WW);                                     \
      const int rr = min(max(y0 - virt_row0 + 1, 0), NSLOT - 2);               \
      const uint32_t* rp0 = smem + rr * SLOTQ + (PHALF) + 4 * (xc + 1);        \
      const uint32_t* rp1 = rp0 + SLOTQ;                                       \
      float dA, dB, dC, dD;                                                    \
      DOT8(rp0,     L0, L1, L2, L3, dA)                                        \
      DOT8(rp0 + 4, L0, L1, L2, L3, dB)                                        \
      DOT8(rp1,     L0, L1, L2, L3, dC)                                        \
      DOT8(rp1 + 4, L0, L1, L2, L3, dD)                                        \
      acc[S] += fmaf(wA, dA, fmaf(wB, dB, fmaf(wC, dC, wD * dD)));             \
    } else {                                                                   \
      const int cx0 = min(max(x0, 0), WW - 1), cx1 = min(max(x1, 0), WW - 1);  \
      const int cy0 = min(max(y0, 0), HH - 1), cy1 = min(max(y1, 0), HH - 1);  \
      _Pragma("unroll")                                                        \
      for (int p_ = 0; p_ < 4; ++p_) {                                         \
        const h2v lvp_ = (p_ == 0) ? u2h(L0) : (p_ == 1) ? u2h(L1)             \
                        : (p_ == 2) ? u2h(L2) : u2h(L3);                       \
        _Pragma("unroll")                                                      \
        for (int c2_ = 0; c2_ < 2; ++c2_) {                                    \
          const float* rq_ = rnb + (size_t)(gch + (CHB) + 2 * p_ + c2_) * HW;  \
          const float v_ = wA * rq_[cy0 * WW + cx0] + wB * rq_[cy0 * WW + cx1] \
                         + wC * rq_[cy1 * WW + cx0] + wD * rq_[cy1 * WW + cx1];\
          acc[S] += (c2_ ? (float)lvp_.y : (float)lvp_.x) * v_;                \
        }                                                                      \
      }                                                                        \
    }                                                                          \
  }

// staging: issue 8 channel loads for one column pass (flight regs f0..f7)
#define SLOAD(PASS, CHB)                                                       \
  if (wv < nrows) {                                                            \
    const int cq_ = 64 * (PASS) + lane;                                        \
    const float* s0_ = rnb + (size_t)(gch + (CHB)) * HW                        \
                     + (row0 + wv) * WW + cq_;                                 \
    f0 = s0_[0];      f1 = s0_[HW];     f2 = s0_[2 * HW]; f3 = s0_[3 * HW];    \
    f4 = s0_[4 * HW]; f5 = s0_[5 * HW]; f6 = s0_[6 * HW]; f7 = s0_[7 * HW];    \
  }

// staging: convert + write one column pass into half PHALF
#define SSTORE(PASS, PHALF)                                                    \
  if (wv < nrows) {                                                            \
    const int cq_ = 64 * (PASS) + lane;                                        \
    uint32_t* d_ = &smem[(sbase + wv) * SLOTQ + (PHALF) + 4 * (cq_ + 1)];      \
    *(uint4*)d_ = make_uint4(pkrtz(f0, f1), pkrtz(f2, f3),                     \
                             pkrtz(f4, f5), pkrtz(f6, f7));                    \
  }

__global__ __launch_bounds__(1024) void corr_kernel(
    const float* __restrict__ left, const float* __restrict__ right,
    const float* __restrict__ eo, float* __restrict__ out)
{
    __shared__ uint32_t smem[SMEMDW];

    const int tid = threadIdx.x;
    const int lane = tid & 63;
    const int wv = tid >> 6;                 // wave 0..15
    const int bid = blockIdx.x;
    const int g = bid & (GG - 1);
    const int h0 = ((bid >> 3) & 15) << 2;
    const int n = bid >> 7;
    const int gch = g * CG;

    const int virt_row0 = h0 - RW;                        // slot 1 maps here
    const int row0 = max(0, virt_row0);
    const int row_last = min(HH - 1, h0 + TY + RW - 1);   // h0+8 interior
    const int nrows = row_last - row0 + 1;                // <= 14
    const int sbase = row0 - virt_row0 + 1;

    const int hh = tid >> 8;                 // 0..3 (wave-uniform)
    const int h = h0 + hh;
    const int wcol = tid & 255;
    const int pix = h * WW + wcol;

    const float* rnb = right + (size_t)n * CC * HW;
    const float* lp  = left  + (size_t)(n * CC + gch) * HW + pix;
    const float* eob = eo + (size_t)n * SS * 2 * HW + pix;

    // zero LDS (guard slots/cols + pads must read f16 0.0 = 0x0000)
    for (int i = tid; i < SMEMDW / 4; i += 1024)
        *(uint4*)&smem[4 * i] = make_uint4(0u, 0u, 0u, 0u);
    __syncthreads();

    float f0, f1, f2, f3, f4, f5, f6, f7;    // staging flight regs

    // ---- stage LO half (ch 0..7) straight ----
#pragma unroll
    for (int pass = 0; pass < 4; ++pass) {
        SLOAD(pass, 0)
        SSTORE(pass, 0)
    }

    // left values, packed per pair (8 regs, held)
    uint32_t lv0, lv1, lv2, lv3, lv4, lv5, lv6, lv7;
    lv0 = pkrtz(lp[0],          lp[(size_t)1 * HW]);
    lv1 = pkrtz(lp[(size_t)2 * HW],  lp[(size_t)3 * HW]);
    lv2 = pkrtz(lp[(size_t)4 * HW],  lp[(size_t)5 * HW]);
    lv3 = pkrtz(lp[(size_t)6 * HW],  lp[(size_t)7 * HW]);
    lv4 = pkrtz(lp[(size_t)8 * HW],  lp[(size_t)9 * HW]);
    lv5 = pkrtz(lp[(size_t)10 * HW], lp[(size_t)11 * HW]);
    lv6 = pkrtz(lp[(size_t)12 * HW], lp[(size_t)13 * HW]);
    lv7 = pkrtz(lp[(size_t)14 * HW], lp[(size_t)15 * HW]);

    float acc[SS];
#pragma unroll
    for (int s = 0; s < SS; ++s) acc[s] = 0.0f;

    __syncthreads();                 // lo half staged

    // ---- hi staging (issue-early/write-late) interleaved with lo compute ----
    SLOAD(0, 8)
    SHALF(0, 0, 0, lv0, lv1, lv2, lv3)
    SHALF(1, 0, 0, lv0, lv1, lv2, lv3)
    SHALF(2, 0, 0, lv0, lv1, lv2, lv3)
    SSTORE(0, HALFDW)
    SLOAD(1, 8)
    SHALF(3, 0, 0, lv0, lv1, lv2, lv3)
    SHALF(4, 0, 0, lv0, lv1, lv2, lv3)
    SHALF(5, 0, 0, lv0, lv1, lv2, lv3)
    SSTORE(1, HALFDW)
    SLOAD(2, 8)
    SHALF(6, 0, 0, lv0, lv1, lv2, lv3)
    SHALF(7, 0, 0, lv0, lv1, lv2, lv3)
    SHALF(8, 0, 0, lv0, lv1, lv2, lv3)
    SSTORE(2, HALFDW)
    SLOAD(3, 8)
    SSTORE(3, HALFDW)

    __syncthreads();                 // hi half staged

    SHALF(0, HALFDW, 8, lv4, lv5, lv6, lv7)
    SHALF(1, HALFDW, 8, lv4, lv5, lv6, lv7)
    SHALF(2, HALFDW, 8, lv4, lv5, lv6, lv7)
    SHALF(3, HALFDW, 8, lv4, lv5, lv6, lv7)
    SHALF(4, HALFDW, 8, lv4, lv5, lv6, lv7)
    SHALF(5, HALFDW, 8, lv4, lv5, lv6, lv7)
    SHALF(6, HALFDW, 8, lv4, lv5, lv6, lv7)
    SHALF(7, HALFDW, 8, lv4, lv5, lv6, lv7)
    SHALF(8, HALFDW, 8, lv4, lv5, lv6, lv7)

    float* ob = out + ((size_t)(n * GG + g) * SS) * HW + pix;
#pragma unroll
    for (int s = 0; s < SS; ++s)
        ob[s * HW] = acc[s] * (1.0f / CG);
}

extern "C" void kernel_launch(void* const* d_in, const int* in_sizes, int n_in,
                              void* d_out, int out_size, void* d_ws, size_t ws_size,
                              hipStream_t stream) {
    const float* left  = (const float*)d_in[0];
    const float* right = (const float*)d_in[1];
    const float* eo    = (const float*)d_in[2];
    float* out = (float*)d_out;
    (void)d_ws; (void)ws_size; (void)in_sizes; (void)n_in; (void)out_size;

    dim3 grid(NB * (HH / TY) * GG);   // 256 blocks: (n, h-tile, group)
    dim3 block(1024);                  // 16 waves; thread = (hh, w)
    corr_kernel<<<grid, block, 0, stream>>>(left, right, eo, out);
}

// Round 21
// 24.270 us; speedup vs baseline: 1.0450x; 1.0450x over previous
//
#include <hip/hip_runtime.h>
#include <stdint.h>

// Deformable 3x3 local correlation. f16 channel-major SPLIT-CELL LDS (r18,
// 21.1us) + HOISTED per-s state: eo loads, addresses, and f16-packed weights
// computed BEFORE the staging barrier (overlapped with staging latency --
// syncthreads' fence blocks the compiler from doing this hoist itself, r19
// showed setup is ~20% of runtime). Post-barrier s-loop is pure
// gather+fdot2+store. Guard-only LDS zeroing (data cells fully overwritten).
// r19 lesson: duplicating setup costs more than staging latency hidden.
// r16 lesson: cells must stay 16B-aligned for b128.
// r6-r13 lesson: 64-VGPR cap not overridable; WRITE_SIZE >> 9.2MB = spill.
// left/right (2,128,64,256) f32, extra_offset (2,18,64,256) f32,
// out (2,72,64,256) f32. GROUPS=8, cg=16, S=9.

#define NB 2
#define CC 128
#define HH 64
#define WW 256
#define GG 8
#define CG 16
#define SS 9
#define HW (HH * WW)
#define TY 4                      // output rows per block
#define RW 5                      // staged rows h0-RW .. h0+TY+RW-1 (14 interior)
#define NSLOT 16                  // 1 top guard + 14 data + 1 bottom guard
#define HALFDW 1056               // dwords per half-row (258 cells x 4dw, padded)
#define SLOTQ (2 * HALFDW)        // 2112 dwords per row slot
#define SMEMDW (NSLOT * SLOTQ)    // 33792 dw = 135.2 KB -> 1 block/CU

typedef __fp16 h2v __attribute__((ext_vector_type(2)));

static __device__ __forceinline__ uint32_t pkrtz(float a, float b) {
    h2v v = __builtin_amdgcn_cvt_pkrtz(a, b);
    return __builtin_bit_cast(uint32_t, v);
}
static __device__ __forceinline__ h2v u2h(uint32_t u) {
    return __builtin_bit_cast(h2v, u);
}

#if __has_builtin(__builtin_amdgcn_fdot2)
#define FDOT2(A, B, C) __builtin_amdgcn_fdot2((A), (B), (C), false)
#else
#define FDOT2(A, B, C) fmaf((float)(A).x, (float)(B).x, \
                            fmaf((float)(A).y, (float)(B).y, (C)))
#endif

// 16-channel dot at one (row,col): lo b128 (pairs 0-3) + hi b128 (pairs 4-7)
#define DOT16(LOP, RES)                                                        \
  {                                                                            \
    const uint4 u0_ = *(const uint4*)(LOP);                                    \
    const uint4 u1_ = *(const uint4*)((LOP) + HALFDW);                         \
    RES = FDOT2(u2h(u0_.x), u2h(lvpk[0]),                                      \
          FDOT2(u2h(u0_.y), u2h(lvpk[1]),                                      \
          FDOT2(u2h(u0_.z), u2h(lvpk[2]),                                      \
          FDOT2(u2h(u0_.w), u2h(lvpk[3]),                                      \
          FDOT2(u2h(u1_.x), u2h(lvpk[4]),                                      \
          FDOT2(u2h(u1_.y), u2h(lvpk[5]),                                      \
          FDOT2(u2h(u1_.z), u2h(lvpk[6]),                                      \
          FDOT2(u2h(u1_.w), u2h(lvpk[7]), 0.0f))))))));                        \
  }

__global__ __launch_bounds__(1024) void corr_kernel(
    const float* __restrict__ left, const float* __restrict__ right,
    const float* __restrict__ eo, float* __restrict__ out)
{
    __shared__ uint32_t smem[SMEMDW];

    const int tid = threadIdx.x;
    const int lane = tid & 63;
    const int wv = tid >> 6;                 // wave 0..15
    const int bid = blockIdx.x;
    const int g = bid & (GG - 1);
    const int h0 = ((bid >> 3) & 15) << 2;
    const int n = bid >> 7;
    const int gch = g * CG;

    const int virt_row0 = h0 - RW;                        // slot 1 maps here
    const int row0 = max(0, virt_row0);
    const int row_last = min(HH - 1, h0 + TY + RW - 1);   // h0+8 interior
    const int nrows = row_last - row0 + 1;                // <= 14
    const int sbase = row0 - virt_row0 + 1;

    const int hh = tid >> 8;                 // 0..3 (wave-uniform)
    const int h = h0 + hh;
    const int wcol = tid & 255;
    const int pix = h * WW + wcol;

    const float* rnb = right + (size_t)n * CC * HW;
    const float* lp  = left  + (size_t)(n * CC + gch) * HW + pix;
    const float* eob = eo + (size_t)n * SS * 2 * HW + pix;

    // ---- guard-only zeroing: wave wv owns slot wv ----
    // unstaged slots fully zeroed; staged slots only guard cells (cell 0 and
    // cell 257 of each half). Data cells are fully overwritten by staging.
    {
        const bool staged = (wv >= sbase) && (wv < sbase + nrows);
        uint32_t* slot = &smem[wv * SLOTQ];
        if (!staged) {
            for (int i = lane; i < SLOTQ / 4; i += 64)
                *(uint4*)&slot[4 * i] = make_uint4(0u, 0u, 0u, 0u);
        } else if (lane < 16) {
            const int half = lane >> 3;          // 0: lo, 1: hi
            const int cellsel = (lane >> 2) & 1; // 0: cell 0, 1: cell 257
            const int dwi = lane & 3;
            slot[half * HALFDW + cellsel * (257 * 4) + dwi] = 0u;
        }
    }

    // ---- issue eo + left loads early (latency overlaps staging below) ----
    float eox[SS], eoy[SS];
#pragma unroll
    for (int s = 0; s < SS; ++s) {
        eox[s] = eob[(2 * s) * HW];
        eoy[s] = eob[(2 * s + 1) * HW];
    }
    float lf[CG];
#pragma unroll
    for (int c = 0; c < CG; ++c) lf[c] = lp[(size_t)c * HW];

    __syncthreads();                 // zeroing visible before staging writes

    // ---- stage all 16 channels, 4 column passes ----
#pragma unroll
    for (int pass = 0; pass < 4; ++pass) {
        if (wv < nrows) {
            const int cq = 64 * pass + lane;             // col 0..255
            const float* s0 = rnb + (size_t)gch * HW + (row0 + wv) * WW + cq;
            uint32_t pk8[8];
#pragma unroll
            for (int p = 0; p < 8; ++p)
                pk8[p] = pkrtz(s0[(size_t)(2 * p) * HW],
                               s0[(size_t)(2 * p + 1) * HW]);
            uint32_t* dst = &smem[(sbase + wv) * SLOTQ + 4 * (cq + 1)];
            *(uint4*)dst            = make_uint4(pk8[0], pk8[1], pk8[2], pk8[3]);
            *(uint4*)(dst + HALFDW) = make_uint4(pk8[4], pk8[5], pk8[6], pk8[7]);
        }
    }

    // ---- pack left values; precompute per-s state (overlaps staging) ----
    uint32_t lvpk[8];
#pragma unroll
    for (int p = 0; p < 8; ++p)
        lvpk[p] = pkrtz(lf[2 * p], lf[2 * p + 1]);

    int lbase[SS];
    uint32_t wab[SS], wcd[SS];
    int badmask = 0;
#pragma unroll
    for (int s = 0; s < SS; ++s) {
        const float x = (float)(s / 3 - 1) + eox[s] + (float)wcol;
        const float y = (float)(s % 3 - 1) + eoy[s] + (float)h;
        const float x0f = floorf(x), y0f = floorf(y);
        const float fx0 = x - x0f, fx1 = 1.0f - fx0;
        const float fy0 = y - y0f, fy1 = 1.0f - fy0;
        const int x0 = (int)x0f, y0 = (int)y0f;
        const int x1 = x0 + 1,   y1 = y0 + 1;
        const bool vx0 = (unsigned)x0 < (unsigned)WW;
        const bool vx1 = (unsigned)x1 < (unsigned)WW;
        const bool vy0 = (unsigned)y0 < (unsigned)HH;
        const bool vy1 = (unsigned)y1 < (unsigned)HH;
        const float wA = (vx0 && vy0) ? fx1 * fy1 : 0.0f;   // (x0,y0)
        const float wB = (vx1 && vy0) ? fx0 * fy1 : 0.0f;   // (x1,y0)
        const float wC = (vx0 && vy1) ? fx1 * fy0 : 0.0f;   // (x0,y1)
        const float wD = (vx1 && vy1) ? fx0 * fy0 : 0.0f;   // (x1,y1)
        wab[s] = pkrtz(wA, wB);
        wcd[s] = pkrtz(wC, wD);
        const int xc = min(max(x0, -1), WW);                       // [-1,256]
        const int rr = min(max(y0 - virt_row0 + 1, 0), NSLOT - 2); // [0,14]
        lbase[s] = rr * SLOTQ + 4 * (xc + 1);
        if ((vy0 && (y0 < row0 || y0 > row_last)) ||
            (vy1 && (y1 < row0 || y1 > row_last)))
            badmask |= 1 << s;
    }

    __syncthreads();                 // all channels staged

    float* ob = out + ((size_t)(n * GG + g) * SS) * HW + pix;

    // ---- pure gather + dot loop ----
#pragma unroll
    for (int s = 0; s < SS; ++s) {
        float val;
        if (__builtin_expect(!((badmask >> s) & 1), 1)) {
            const uint32_t* rp0 = smem + lbase[s];
            const uint32_t* rp1 = rp0 + SLOTQ;
            float dA, dB, dC, dD;
            DOT16(rp0,     dA)        // (x0,y0)
            DOT16(rp0 + 4, dB)        // (x1,y0)
            DOT16(rp1,     dC)        // (x0,y1)
            DOT16(rp1 + 4, dD)        // (x1,y1)
            const h2v w01 = u2h(wab[s]), w23 = u2h(wcd[s]);
            val = fmaf((float)w01.x, dA, fmaf((float)w01.y, dB,
                  fmaf((float)w23.x, dC, (float)w23.y * dD)));
        } else {
            // ~never (needs |eo| > ~4 sigma): full-precision global fallback
            const float x = (float)(s / 3 - 1) + eob[(2 * s) * HW] + (float)wcol;
            const float y = (float)(s % 3 - 1) + eob[(2 * s + 1) * HW] + (float)h;
            const float x0f = floorf(x), y0f = floorf(y);
            const float fx0 = x - x0f, fx1 = 1.0f - fx0;
            const float fy0 = y - y0f, fy1 = 1.0f - fy0;
            const int x0 = (int)x0f, y0 = (int)y0f;
            const int x1 = x0 + 1,   y1 = y0 + 1;
            const bool vx0 = (unsigned)x0 < (unsigned)WW;
            const bool vx1 = (unsigned)x1 < (unsigned)WW;
            const bool vy0 = (unsigned)y0 < (unsigned)HH;
            const bool vy1 = (unsigned)y1 < (unsigned)HH;
            const float a = (vx0 && vy0) ? fx1 * fy1 : 0.0f;
            const float b = (vx1 && vy0) ? fx0 * fy1 : 0.0f;
            const float c3 = (vx0 && vy1) ? fx1 * fy0 : 0.0f;
            const float d = (vx1 && vy1) ? fx0 * fy0 : 0.0f;
            const int cx0 = min(max(x0, 0), WW - 1), cx1 = min(max(x1, 0), WW - 1);
            const int cy0 = min(max(y0, 0), HH - 1), cy1 = min(max(y1, 0), HH - 1);
            val = 0.0f;
#pragma unroll
            for (int p = 0; p < 8; ++p) {
                const h2v lv = u2h(lvpk[p]);
#pragma unroll
                for (int c2 = 0; c2 < 2; ++c2) {
                    const float* rp2 = rnb + (size_t)(gch + 2 * p + c2) * HW;
                    const float v = a * rp2[cy0 * WW + cx0] + b * rp2[cy0 * WW + cx1]
                                  + c3 * rp2[cy1 * WW + cx0] + d * rp2[cy1 * WW + cx1];
                    val += (c2 ? (float)lv.y : (float)lv.x) * v;
                }
            }
        }
        ob[s * HW] = val * (1.0f / CG);
    }
}

extern "C" void kernel_launch(void* const* d_in, const int* in_sizes, int n_in,
                              void* d_out, int out_size, void* d_ws, size_t ws_size,
                              hipStream_t stream) {
    const float* left  = (const float*)d_in[0];
    const float* right = (const float*)d_in[1];
    const float* eo    = (const float*)d_in[2];
    float* out = (float*)d_out;
    (void)d_ws; (void)ws_size; (void)in_sizes; (void)n_in; (void)out_size;

    dim3 grid(NB * (HH / TY) * GG);   // 256 blocks: (n, h-tile, group)
    dim3 block(1024);                  // 16 waves; thread = (hh, w)
    corr_kernel<<<grid, block, 0, stream>>>(left, right, eo, out);
}

// Round 22
// 20.996 us; speedup vs baseline: 1.2080x; 1.1560x over previous
//
#include <hip/hip_runtime.h>
#include <stdint.h>

// Deformable 3x3 local correlation. f16 channel-major SPLIT-CELL LDS (r18
// structure, 21.1us best) with exactly two bounded additions:
//  (1) the 18 extra_offset loads hoisted BEFORE the staging barrier (long-
//      latency globals; fence otherwise serializes them post-barrier). Only
//      ~26 regs live across the barrier -- r21 cached ~69 and spilled.
//  (2) guard-only LDS zeroing (data cells fully overwritten by staging).
// Weight/address VALU stays post-barrier (r19: duplicating it costs more;
// r21: caching it spills). r16: cells must stay 16B-aligned for b128.
// r6-r13: 64-VGPR cap not overridable; WRITE_SIZE >> 9.2MB = spill tripwire.
// left/right (2,128,64,256) f32, extra_offset (2,18,64,256) f32,
// out (2,72,64,256) f32. GROUPS=8, cg=16, S=9.

#define NB 2
#define CC 128
#define HH 64
#define WW 256
#define GG 8
#define CG 16
#define SS 9
#define HW (HH * WW)
#define TY 4                      // output rows per block
#define RW 5                      // staged rows h0-RW .. h0+TY+RW-1 (14 interior)
#define NSLOT 16                  // 1 top guard + 14 data + 1 bottom guard
#define HALFDW 1056               // dwords per half-row (258 cells x 4dw, padded)
#define SLOTQ (2 * HALFDW)        // 2112 dwords per row slot
#define SMEMDW (NSLOT * SLOTQ)    // 33792 dw = 135.2 KB -> 1 block/CU

typedef __fp16 h2v __attribute__((ext_vector_type(2)));

static __device__ __forceinline__ uint32_t pkrtz(float a, float b) {
    h2v v = __builtin_amdgcn_cvt_pkrtz(a, b);
    return __builtin_bit_cast(uint32_t, v);
}
static __device__ __forceinline__ h2v u2h(uint32_t u) {
    return __builtin_bit_cast(h2v, u);
}

#if __has_builtin(__builtin_amdgcn_fdot2)
#define FDOT2(A, B, C) __builtin_amdgcn_fdot2((A), (B), (C), false)
#else
#define FDOT2(A, B, C) fmaf((float)(A).x, (float)(B).x, \
                            fmaf((float)(A).y, (float)(B).y, (C)))
#endif

// 16-channel dot at one (row,col): lo b128 (pairs 0-3) + hi b128 (pairs 4-7)
#define DOT16(LOP, RES)                                                        \
  {                                                                            \
    const uint4 u0_ = *(const uint4*)(LOP);                                    \
    const uint4 u1_ = *(const uint4*)((LOP) + HALFDW);                         \
    RES = FDOT2(u2h(u0_.x), u2h(lvpk[0]),                                      \
          FDOT2(u2h(u0_.y), u2h(lvpk[1]),                                      \
          FDOT2(u2h(u0_.z), u2h(lvpk[2]),                                      \
          FDOT2(u2h(u0_.w), u2h(lvpk[3]),                                      \
          FDOT2(u2h(u1_.x), u2h(lvpk[4]),                                      \
          FDOT2(u2h(u1_.y), u2h(lvpk[5]),                                      \
          FDOT2(u2h(u1_.z), u2h(lvpk[6]),                                      \
          FDOT2(u2h(u1_.w), u2h(lvpk[7]), 0.0f))))))));                        \
  }

__global__ __launch_bounds__(1024) void corr_kernel(
    const float* __restrict__ left, const float* __restrict__ right,
    const float* __restrict__ eo, float* __restrict__ out)
{
    __shared__ uint32_t smem[SMEMDW];

    const int tid = threadIdx.x;
    const int lane = tid & 63;
    const int wv = tid >> 6;                 // wave 0..15
    const int bid = blockIdx.x;
    const int g = bid & (GG - 1);
    const int h0 = ((bid >> 3) & 15) << 2;
    const int n = bid >> 7;
    const int gch = g * CG;

    const int virt_row0 = h0 - RW;                        // slot 1 maps here
    const int row0 = max(0, virt_row0);
    const int row_last = min(HH - 1, h0 + TY + RW - 1);   // h0+8 interior
    const int nrows = row_last - row0 + 1;                // <= 14
    const int sbase = row0 - virt_row0 + 1;

    const int hh = tid >> 8;                 // 0..3 (wave-uniform)
    const int h = h0 + hh;
    const int wcol = tid & 255;
    const int pix = h * WW + wcol;

    const float* rnb = right + (size_t)n * CC * HW;
    const float* lp  = left  + (size_t)(n * CC + gch) * HW + pix;
    const float* eob = eo + (size_t)n * SS * 2 * HW + pix;

    // ---- guard-only zeroing: wave wv owns slot wv ----
    // unstaged slots fully zeroed; staged slots only guard cells (cell 0 and
    // cell 257 of each half). Data cells are fully overwritten by staging.
    {
        const bool staged = (wv >= sbase) && (wv < sbase + nrows);
        uint32_t* slot = &smem[wv * SLOTQ];
        if (!staged) {
            for (int i = lane; i < SLOTQ / 4; i += 64)
                *(uint4*)&slot[4 * i] = make_uint4(0u, 0u, 0u, 0u);
        } else if (lane < 16) {
            const int half = lane >> 3;          // 0: lo, 1: hi
            const int cellsel = (lane >> 2) & 1; // 0: cell 0, 1: cell 257
            const int dwi = lane & 3;
            slot[half * HALFDW + cellsel * (257 * 4) + dwi] = 0u;
        }
    }

    // ---- hoist the 18 eo loads (latency overlaps staging below) ----
    float eox[SS], eoy[SS];
#pragma unroll
    for (int s = 0; s < SS; ++s) {
        eox[s] = eob[(2 * s) * HW];
        eoy[s] = eob[(2 * s + 1) * HW];
    }

    __syncthreads();                 // zeroing visible before staging writes

    // ---- stage all 16 channels, 4 column passes ----
#pragma unroll
    for (int pass = 0; pass < 4; ++pass) {
        if (wv < nrows) {
            const int cq = 64 * pass + lane;             // col 0..255
            const float* s0 = rnb + (size_t)gch * HW + (row0 + wv) * WW + cq;
            uint32_t pk8[8];
#pragma unroll
            for (int p = 0; p < 8; ++p)
                pk8[p] = pkrtz(s0[(size_t)(2 * p) * HW],
                               s0[(size_t)(2 * p + 1) * HW]);
            uint32_t* dst = &smem[(sbase + wv) * SLOTQ + 4 * (cq + 1)];
            *(uint4*)dst            = make_uint4(pk8[0], pk8[1], pk8[2], pk8[3]);
            *(uint4*)(dst + HALFDW) = make_uint4(pk8[4], pk8[5], pk8[6], pk8[7]);
        }
    }

    // left values, packed per pair (computed while staging drains)
    uint32_t lvpk[8];
#pragma unroll
    for (int p = 0; p < 8; ++p)
        lvpk[p] = pkrtz(lp[(size_t)(2 * p) * HW], lp[(size_t)(2 * p + 1) * HW]);

    float acc[SS];
#pragma unroll
    for (int s = 0; s < SS; ++s) acc[s] = 0.0f;

    __syncthreads();                 // all channels staged

    // ---- per-s: setup (from hoisted eo) + gather + dot ----
#pragma unroll
    for (int s = 0; s < SS; ++s) {
        const float x = (float)(s / 3 - 1) + eox[s] + (float)wcol;
        const float y = (float)(s % 3 - 1) + eoy[s] + (float)h;
        const float x0f = floorf(x), y0f = floorf(y);
        const float fx0 = x - x0f, fx1 = 1.0f - fx0;
        const float fy0 = y - y0f, fy1 = 1.0f - fy0;
        const int x0 = (int)x0f, y0 = (int)y0f;
        const int x1 = x0 + 1,   y1 = y0 + 1;
        const bool vx0 = (unsigned)x0 < (unsigned)WW;
        const bool vx1 = (unsigned)x1 < (unsigned)WW;
        const bool vy0 = (unsigned)y0 < (unsigned)HH;
        const bool vy1 = (unsigned)y1 < (unsigned)HH;
        const float wA = (vx0 && vy0) ? fx1 * fy1 : 0.0f;   // (x0,y0)
        const float wB = (vx1 && vy0) ? fx0 * fy1 : 0.0f;   // (x1,y0)
        const float wC = (vx0 && vy1) ? fx1 * fy0 : 0.0f;   // (x0,y1)
        const float wD = (vx1 && vy1) ? fx0 * fy0 : 0.0f;   // (x1,y1)

        const bool bad = (vy0 && (y0 < row0 || y0 > row_last)) ||
                         (vy1 && (y1 < row0 || y1 > row_last));

        if (__builtin_expect(!bad, 1)) {
            const int xc = min(max(x0, -1), WW);                       // [-1,256]
            const int rr = min(max(y0 - virt_row0 + 1, 0), NSLOT - 2); // [0,14]
            const uint32_t* rp0 = smem + rr * SLOTQ + 4 * (xc + 1);
            const uint32_t* rp1 = rp0 + SLOTQ;
            float dA, dB, dC, dD;
            DOT16(rp0,     dA)        // (x0,y0)
            DOT16(rp0 + 4, dB)        // (x1,y0)
            DOT16(rp1,     dC)        // (x0,y1)
            DOT16(rp1 + 4, dD)        // (x1,y1)
            acc[s] += fmaf(wA, dA, fmaf(wB, dB, fmaf(wC, dC, wD * dD)));
        } else {
            // ~never (needs |eo| > ~4 sigma): full-precision global fallback
            const int cx0 = min(max(x0, 0), WW - 1), cx1 = min(max(x1, 0), WW - 1);
            const int cy0 = min(max(y0, 0), HH - 1), cy1 = min(max(y1, 0), HH - 1);
#pragma unroll
            for (int p = 0; p < 8; ++p) {
                const h2v lv = u2h(lvpk[p]);
#pragma unroll
                for (int c2 = 0; c2 < 2; ++c2) {
                    const float* rp2 = rnb + (size_t)(gch + 2 * p + c2) * HW;
                    const float v = wA * rp2[cy0 * WW + cx0] + wB * rp2[cy0 * WW + cx1]
                                  + wC * rp2[cy1 * WW + cx0] + wD * rp2[cy1 * WW + cx1];
                    acc[s] += (c2 ? (float)lv.y : (float)lv.x) * v;
                }
            }
        }
    }

    float* ob = out + ((size_t)(n * GG + g) * SS) * HW + pix;
#pragma unroll
    for (int s = 0; s < SS; ++s)
        ob[s * HW] = acc[s] * (1.0f / CG);
}

extern "C" void kernel_launch(void* const* d_in, const int* in_sizes, int n_in,
                              void* d_out, int out_size, void* d_ws, size_t ws_size,
                              hipStream_t stream) {
    const float* left  = (const float*)d_in[0];
    const float* right = (const float*)d_in[1];
    const float* eo    = (const float*)d_in[2];
    float* out = (float*)d_out;
    (void)d_ws; (void)ws_size; (void)in_sizes; (void)n_in; (void)out_size;

    dim3 grid(NB * (HH / TY) * GG);   // 256 blocks: (n, h-tile, group)
    dim3 block(1024);                  // 16 waves; thread = (hh, w)
    corr_kernel<<<grid, block, 0, stream>>>(left, right, eo, out);
}